// Round 1
// baseline (378.696 us; speedup 1.0000x reference)
//
#include <hip/hip_runtime.h>

#define T_SEQ 512
#define HID   50
#define NB    8           // batch rows per block (MFMA N=16: cols 0-7 = L0 batch, 8-15 = L1 batch)
#define BLK   832         // 13 waves; wave w owns L0 Mtile w AND L1 Mtile w

typedef float v4f  __attribute__((ext_vector_type(4)));
typedef _Float16 f16;
typedef f16  f16x8 __attribute__((ext_vector_type(8)));

// R11 = R10 with LAYER-MERGED waves: each wave computes L0 Mtile w (C0) and
// L1 Mtile w (C1) every superstep, sharing the hA B-frags (B0,B1) in-register
// between both layers' MFMAs.  C1 is packed into cols 8-15 via shfl_xor(8),
// so ONE fully-valid UPDW per wave:  13 UPDWs/step (minimum) vs R10's 16,
// waves 16->13, swizzles 64->52.  Per-lane tb/active selects handle the
// layer split inside the (lane-uniform) epilogue math.
// B-frag tiles (f16, 8 k-tiles of 32): 0,1=hA buf0 (x@k62,1@k63); 2,3=hA buf1;
// 4,5=hB buf0; 6,7=hB buf1. Superstep s: rb=(s+1)&1, wb=s&1 (hazards: R9 proof).
// MFMA 16x16x32_f16: A[m=lane&15][k=(lane>>4)*8+j]; B[k=(lane>>4)*8+j][n=lane&15];
// C reg r = C[row=(lane>>4)*4+r][col=lane&15].  M layout: m=4u+g (gate-interleaved).

__device__ __forceinline__ f16x8 ldA0(const float* __restrict__ Whh0,
                                      const float* __restrict__ Wih0,
                                      const float* __restrict__ bih0,
                                      const float* __restrict__ bhh0,
                                      int m, int kb) {
    const int u = m >> 2, g = m & 3;
    f16x8 v;
    #pragma unroll
    for (int j = 0; j < 8; ++j) {
        const int k = kb + j;
        float f = 0.f;
        if (u < HID) {
            const int rho = g * HID + u;
            if (k < HID)      f = Whh0[rho * HID + k];
            else if (k == 62) f = Wih0[rho];
            else if (k == 63) f = bih0[rho] + bhh0[rho];
        }
        v[j] = (f16)f;
    }
    return v;
}

__device__ __forceinline__ f16x8 ldA1a(const float* __restrict__ Wih1,
                                       const float* __restrict__ bih1,
                                       const float* __restrict__ bhh1,
                                       int m, int kb) {
    const int u = m >> 2, g = m & 3;
    f16x8 v;
    #pragma unroll
    for (int j = 0; j < 8; ++j) {
        const int k = kb + j;
        float f = 0.f;
        if (u < HID) {
            const int rho = g * HID + u;
            if (k < HID)      f = Wih1[rho * HID + k];
            else if (k == 63) f = bih1[rho] + bhh1[rho];
        }
        v[j] = (f16)f;
    }
    return v;
}

__device__ __forceinline__ f16x8 ldA1b(const float* __restrict__ Whh1,
                                       int m, int kb) {
    const int u = m >> 2, g = m & 3;
    f16x8 v;
    #pragma unroll
    for (int j = 0; j < 8; ++j) {
        const int k = kb + j;
        float f = 0.f;
        if (u < HID && k < HID) f = Whh1[(g * HID + u) * HID + k];
        v[j] = (f16)f;
    }
    return v;
}

#define MFMA16(A, B, C) __builtin_amdgcn_mfma_f32_16x16x32_f16((A), (B), (C), 0, 0, 0)

__global__ __launch_bounds__(BLK, 1)
void lstm2_mfma(const float* __restrict__ x,
                const float* __restrict__ Wih0,
                const float* __restrict__ Whh0,
                const float* __restrict__ bih0,
                const float* __restrict__ bhh0,
                const float* __restrict__ Wih1,
                const float* __restrict__ Whh1,
                const float* __restrict__ bih1,
                const float* __restrict__ bhh1,
                const float* __restrict__ Wfc,
                const float* __restrict__ bfc,
                float* __restrict__ out)
{
    __shared__ __align__(16) f16 BPH [8 * 64 * 8];   // 8,192 B: B frags (dbuf hA/hB)
    __shared__ f16   xs16[NB][T_SEQ];                // 8,192 B: staged x (f16)
    __shared__ float hfin[HID][NB];                  // 1,600 B: final hB fp32

    const int tid  = threadIdx.x;
    const int w    = tid >> 6;                       // 0..12 = Mtile index (both layers)
    const int lane = tid & 63;
    const int n16  = lane & 15;
    const int quad = lane >> 4;
    const int bb0  = blockIdx.x * NB;

    const float* xg = x + (long)bb0 * T_SEQ;

    // ---- one-time: zero B frags; stage x -> f16 LDS ----
    for (int i = tid; i < 8 * 64 * 8; i += BLK) BPH[i] = (f16)0.f;
    for (int i = tid; i < NB * T_SEQ; i += BLK) {
        const int n = i >> 9, tt = i & (T_SEQ - 1);
        xs16[n][tt] = (f16)xg[n * T_SEQ + tt];
    }

    // ---- one-time: this wave's weights for BOTH layers, Mtile w ----
    const int m   = w * 16 + n16;
    const int kb0 = quad * 8, kb1 = 32 + quad * 8;
    const f16x8 a0 = ldA0(Whh0, Wih0, bih0, bhh0, m, kb0);   // L0: [Whh0|x|b]
    const f16x8 a1 = ldA0(Whh0, Wih0, bih0, bhh0, m, kb1);
    const f16x8 v0 = ldA1a(Wih1, bih1, bhh1, m, kb0);        // L1: hA-side [Wih1|b]
    const f16x8 v1 = ldA1a(Wih1, bih1, bhh1, m, kb1);
    const f16x8 v2 = ldA1b(Whh1, m, kb0);                    // L1: hB-side Whh1
    const f16x8 v3 = ldA1b(Whh1, m, kb1);

    __syncthreads();
    // "1.0" bias lanes (k=63) in both hA bufs; x(0) into hA buf1 (read at s=0)
    if (tid < NB) {
        BPH[(1 * 64 + 48 + tid) * 8 + 7] = (f16)1.f;
        BPH[(3 * 64 + 48 + tid) * 8 + 7] = (f16)1.f;
        BPH[(3 * 64 + 48 + tid) * 8 + 6] = xs16[tid][0];
    }
    __syncthreads();

    // per-lane cell state: cols 0-7 track L0 cell (u_, n16), cols 8-15 track
    // L1 cell (u_, n16-8).  u_ fixed per lane for all steps.
    const int  u_    = w * 4 + quad;
    const bool isl0  = (n16 < 8);
    const bool valid = (u_ < HID);
    // step-invariant part of the h write address (f16 elements); tile adds tb*512
    const int  wbase = ((u_ >> 5) * 64 + ((u_ & 31) >> 3) * 16 + (n16 & 7)) * 8 + (u_ & 7);
    float cs = 0.f;
    const f16x8* BPF = (const f16x8*)BPH;

    #pragma clang loop unroll(disable)
    for (int s = 0; s <= T_SEQ; ++s) {
        const int rb = (s + 1) & 1, wb = s & 1;

        // shared hA(s-1) frags feed BOTH layers; hB(s-2) frags feed L1 only
        const f16x8 B0 = BPF[(2 * rb + 0) * 64 + lane];
        const f16x8 B1 = BPF[(2 * rb + 1) * 64 + lane];
        const f16x8 B2 = BPF[(4 + 2 * wb + 0) * 64 + lane];
        const f16x8 B3 = BPF[(4 + 2 * wb + 1) * 64 + lane];

        v4f C0 = {0.f, 0.f, 0.f, 0.f};   // L0 Mtile w
        v4f C1 = {0.f, 0.f, 0.f, 0.f};   // L1 Mtile w
        C0 = MFMA16(a0, B0, C0);
        C0 = MFMA16(a1, B1, C0);
        C1 = MFMA16(v0, B0, C1);
        C1 = MFMA16(v1, B1, C1);
        C1 = MFMA16(v2, B2, C1);
        C1 = MFMA16(v3, B3, C1);

        // pack: cols 0-7 <- C0 (L0), cols 8-15 <- C1 shifted up by 8
        const float sx = __shfl_xor(C1.x, 8);
        const float sy = __shfl_xor(C1.y, 8);
        const float sz = __shfl_xor(C1.z, 8);
        const float sw = __shfl_xor(C1.w, 8);
        v4f CC;
        CC.x = isl0 ? C0.x : sx;
        CC.y = isl0 ? C0.y : sy;
        CC.z = isl0 ? C0.z : sz;
        CC.w = isl0 ? C0.w : sw;

        // L0 half computes hA(s) (steps 0..T-1); L1 half computes hB(s-1) (steps 1..T)
        const bool active = isl0 ? (s < T_SEQ) : (s >= 1);

        // ---- packed LSTM epilogue, Montgomery batched rcp (7 transcendentals) ----
        const float e1 = __expf(-CC.x);
        const float e2 = __expf(-CC.y);
        const float e3 = __expf(-2.f * CC.z);
        const float e4 = __expf(-CC.w);
        const float d1 = 1.f + e1, d2 = 1.f + e2, d3 = 1.f + e3, d4 = 1.f + e4;
        const float p2 = d1 * d2, p3 = p2 * d3, p4 = p3 * d4;
        const float i4 = __builtin_amdgcn_rcpf(p4);
        const float go = i4 * p3;                 /* 1/d4 */
        const float i3 = i4 * d4;
        const float r3 = i3 * p2;                 /* 1/d3 */
        const float i2 = i3 * d3;
        const float gf = i2 * d1;                 /* 1/d2 */
        const float gi = i2 * d2;                 /* 1/d1 */
        const float gg = fmaf(2.f, r3, -1.f);
        const float csn = fmaf(gf, cs, gi * gg);
        cs = active ? csn : cs;
        const float th = fmaf(2.f, __builtin_amdgcn_rcpf(1.f + __expf(-2.f * cs)), -1.f);
        const float hh = go * th;

        if (valid && active) {
            const int tb = isl0 ? (2 * wb) : (4 + 2 * rb);
            BPH[tb * 512 + wbase] = (f16)hh;
            if (!isl0 && s == T_SEQ) hfin[u_][n16 & 7] = hh;
        }

        // x(s+1) -> hA write-buf @k62; read at s+1 (one barrier away)
        if (w == 0 && lane < NB && s + 1 < T_SEQ)
            BPH[((2 * wb + 1) * 64 + 48 + lane) * 8 + 6] = xs16[lane][s + 1];

        __syncthreads();   // the ONE barrier: publishes hA(s), hB(s-1), x(s+1)
    }

    // ---- classifier: out[n][c] = hB[n] . Wfc[c] + bfc[c] ----
    if (tid < NB * 2) {
        const int nn = tid >> 1, c = tid & 1;
        float acc = bfc[c];
        #pragma unroll
        for (int u = 0; u < HID; ++u)
            acc = fmaf(Wfc[c * HID + u], hfin[u][nn], acc);
        out[(bb0 + nn) * 2 + c] = acc;
    }
}

extern "C" void kernel_launch(void* const* d_in, const int* in_sizes, int n_in,
                              void* d_out, int out_size, void* d_ws, size_t ws_size,
                              hipStream_t stream) {
    const float* x    = (const float*)d_in[0];
    const float* Wih0 = (const float*)d_in[1];
    const float* Whh0 = (const float*)d_in[2];
    const float* bih0 = (const float*)d_in[3];
    const float* bhh0 = (const float*)d_in[4];
    const float* Wih1 = (const float*)d_in[5];
    const float* Whh1 = (const float*)d_in[6];
    const float* bih1 = (const float*)d_in[7];
    const float* bhh1 = (const float*)d_in[8];
    const float* Wfc  = (const float*)d_in[9];
    const float* bfc  = (const float*)d_in[10];
    float* out = (float*)d_out;

    const int B = in_sizes[0] / T_SEQ;   // D == 1
    const int grid = B / NB;             // 2048/8 = 256 blocks -> 1 block/CU

    hipLaunchKernelGGL(lstm2_mfma, dim3(grid), dim3(BLK), 0, stream,
                       x, Wih0, Whh0, bih0, bhh0, Wih1, Whh1, bih1, bhh1,
                       Wfc, bfc, out);
}